// Round 14
// baseline (414.941 us; speedup 1.0000x reference)
//
#include <hip/hip_runtime.h>
#include <hip/hip_bf16.h>
#include <cstdint>

// Problem constants: B=2, S=4096, C=512, H=8, D=64
#define SB 4096
#define CB 512
#define HB 8
#define DB 64
#define BB 2

// 0.125 * log2(e): folded into Q projection so softmax uses exp2 directly.
#define QSCALE 0.18033688011112042f

typedef __attribute__((ext_vector_type(8))) short s16x8;
typedef __attribute__((ext_vector_type(4))) short s16x4;
typedef __attribute__((ext_vector_type(4))) float f32x4;

__device__ __forceinline__ short f2bf(float f) {
    union { float f; unsigned int u; } v; v.f = f;
    unsigned int r = v.u + 0x7fffu + ((v.u >> 16) & 1u);
    return (short)(r >> 16);
}

// pack two f32 -> bf16 pair (S0 in low half), RNE
__device__ __forceinline__ unsigned int cvtpk(float lo, float hi) {
    unsigned int r;
    asm("v_cvt_pk_bf16_f32 %0, %1, %2" : "=v"(r) : "v"(lo), "v"(hi));
    return r;
}

__device__ __forceinline__ f32x4 mfma16(s16x8 a, s16x8 b, f32x4 c) {
    return __builtin_amdgcn_mfma_f32_16x16x32_bf16(a, b, c, 0, 0, 0);
}

// K=16 bf16 MFMA via inline asm (A/B: 4 bf16 per lane, chunk (lane>>4)*4)
__device__ __forceinline__ f32x4 mfma16x16(s16x4 a, s16x4 b, f32x4 c) {
    asm("v_mfma_f32_16x16x16_bf16 %0, %1, %2, %0" : "+v"(c) : "v"(a), "v"(b));
    return c;
}

// ---------------------------------------------------------------------------
// QKV projection + mask-bitmask (one launch):
// z==0: Q -> bf16 [b,h,s,d] scaled by QSCALE
// z==1: K -> bf16 [b,h,s,d]
// z==2: V -> bf16 [b,h,d,s]  (transposed)
// z>=3: mask -> bitmask chunks (overlaps the proj GEMM; independent work)
// ---------------------------------------------------------------------------
__global__ __launch_bounds__(256) void qkv_mask_kernel(
    const float* __restrict__ q, const float* __restrict__ k, const float* __restrict__ v,
    const float* __restrict__ wq, const float* __restrict__ wk, const float* __restrict__ wv,
    const float* __restrict__ bq, const float* __restrict__ bk, const float* __restrict__ bv,
    unsigned short* __restrict__ Qh, unsigned short* __restrict__ Kh,
    unsigned short* __restrict__ Vt,
    const float* __restrict__ mask, unsigned long long* __restrict__ bits)
{
    const int z = blockIdx.z;
    if (z >= 3) {
        size_t idx = (((size_t)(z - 3) * 512) + blockIdx.y * 64 + blockIdx.x) * 256
                     + threadIdx.x;
        float mv = mask[idx];
        unsigned long long bmask = __ballot(mv != 0.0f);
        if ((threadIdx.x & 63) == 0) bits[idx >> 6] = bmask;
        return;
    }

    const float* X = (z == 0) ? q : (z == 1) ? k : v;
    const float* W = (z == 0) ? wq : (z == 1) ? wk : wv;
    const float* bias = (z == 0) ? bq : (z == 1) ? bk : bv;
    unsigned short* dst = (z == 0) ? Qh : (z == 1) ? Kh : Vt;
    const float oscale = (z == 0) ? QSCALE : 1.0f;
    const int which = (z == 2) ? 2 : 0;

    __shared__ __align__(16) short As[128 * 40];
    __shared__ __align__(16) short Bs[64 * 40];
    const int t = threadIdx.x;
    const int w = t >> 6, lane = t & 63, g = lane >> 4, c = lane & 15;
    const int wr = w >> 1, wc = w & 1;
    const int m0 = blockIdx.x * 128, n0 = blockIdx.y * 64;

    f32x4 acc[4][2];
#pragma unroll
    for (int i = 0; i < 4; ++i)
#pragma unroll
        for (int j = 0; j < 2; ++j) acc[i][j] = (f32x4){0.f, 0.f, 0.f, 0.f};

    for (int k0 = 0; k0 < CB; k0 += 32) {
        __syncthreads();
#pragma unroll
        for (int i = 0; i < 4; ++i) {
            int idx = t + i * 256; int r = idx >> 3, c4 = idx & 7;
            float4 vv = *(const float4*)(X + (size_t)(m0 + r) * CB + k0 + c4 * 4);
            s16x4 p; p[0] = f2bf(vv.x); p[1] = f2bf(vv.y); p[2] = f2bf(vv.z); p[3] = f2bf(vv.w);
            *(s16x4*)&As[r * 40 + c4 * 4] = p;
        }
#pragma unroll
        for (int i = 0; i < 2; ++i) {
            int idx = t + i * 256; int r = idx >> 3, c4 = idx & 7;
            float4 vv = *(const float4*)(W + (size_t)(n0 + r) * CB + k0 + c4 * 4);
            s16x4 p; p[0] = f2bf(vv.x); p[1] = f2bf(vv.y); p[2] = f2bf(vv.z); p[3] = f2bf(vv.w);
            *(s16x4*)&Bs[r * 40 + c4 * 4] = p;
        }
        __syncthreads();
        const int koff = g * 8;
        s16x8 a[4], bb[2];
#pragma unroll
        for (int mf = 0; mf < 4; ++mf)
            a[mf] = *(const s16x8*)&As[(wr * 64 + mf * 16 + c) * 40 + koff];
#pragma unroll
        for (int nf = 0; nf < 2; ++nf)
            bb[nf] = *(const s16x8*)&Bs[(wc * 32 + nf * 16 + c) * 40 + koff];
#pragma unroll
        for (int mf = 0; mf < 4; ++mf)
#pragma unroll
            for (int nf = 0; nf < 2; ++nf)
                acc[mf][nf] = mfma16(a[mf], bb[nf], acc[mf][nf]);
    }

#pragma unroll
    for (int nf = 0; nf < 2; ++nf) {
        const int n = n0 + wc * 32 + nf * 16 + c;
        const float bv2 = bias[n];
        const int h = n >> 6, d = n & 63;
#pragma unroll
        for (int mf = 0; mf < 4; ++mf) {
#pragma unroll
            for (int r = 0; r < 4; ++r) {
                int m = m0 + wr * 64 + mf * 16 + g * 4 + r;
                float val = (acc[mf][nf][r] + bv2) * oscale;
                int b = m >> 12, s = m & (SB - 1);
                size_t off;
                if (which == 0) off = (((size_t)(b * HB + h)) * SB + s) * DB + d;
                else            off = (((size_t)(b * HB + h)) * DB + d) * SB + s;
                dst[off] = (unsigned short)f2bf(val);
            }
        }
    }
}

// ---------------------------------------------------------------------------
// Flash kernel (phase 1) — pair-deep double buffering: 2 k-tiles (128 k-rows)
// per iteration, ONE barrier per pair (33 barriers vs 64). 64 KB LDS; grid
// (512 blocks = 2/CU) already limits residency to 2 blocks/CU, so the larger
// LDS costs no occupancy. 8 waves / 128 q-rows per block, XCD-aware map.
//   loop: LOAD(pair t+1) -> COMPUTE(2t) -> COMPUTE(2t+1) -> STORE -> barrier
// Swapped-operand QK (out[k][q]); per-lane rowsum; PV via 16x16x16 MFMA on
// packed score regs. K/V LDS tiles XOR-swizzled (byte ^= (row&7)<<4).
// Q is pre-scaled by 0.125*log2(e), so e = exp2(QK) directly.
// ---------------------------------------------------------------------------
__global__ __launch_bounds__(512) void flash_kernel(
    const unsigned short* __restrict__ Qh, const unsigned short* __restrict__ Kh,
    const unsigned short* __restrict__ Vt, const unsigned long long* __restrict__ mbits,
    unsigned short* __restrict__ concat, float* __restrict__ invbuf)
{
    __shared__ __align__(16) char Klds[2][128 * 128];   // 2 bufs x 16 KB (128 rows x 128B)
    __shared__ __align__(16) char Vlds[2][64 * 256];    // 2 bufs x 16 KB (64 rows x 256B)

    const int t = threadIdx.x, w = t >> 6, lane = t & 63, g = lane >> 4, c = lane & 15;
    // XCD-aware map: 512 blocks; xcd = bid&7 owns bh {2*xcd, 2*xcd+1}.
    const int bid = blockIdx.x;
    const int xcd = bid & 7, idx = bid >> 3;          // idx in [0,64)
    const int bh = xcd * 2 + (idx >> 5);              // 2 bh per xcd
    const int qb = idx & 31;                          // 32 q-blocks per bh
    const int b = bh >> 3, h = bh & 7;
    const int i0 = qb * 128;

    const unsigned short* Qbase = Qh + ((size_t)bh * SB + i0 + w * 16) * DB;
    const unsigned short* Kbase = Kh + (size_t)bh * SB * DB;
    const unsigned short* Vbase = Vt + (size_t)bh * DB * SB;

    // Q fragments (B-operand): lane c holds Q row (i0+w*16+c), chunk ks*32+g*8
    s16x8 qf[2];
#pragma unroll
    for (int ks = 0; ks < 2; ++ks)
        qf[ks] = *(const s16x8*)(Qbase + (size_t)c * DB + ks * 32 + g * 8);

    const int qrow = i0 + w * 16 + c;
    const size_t mrowbase = (size_t)qrow * (SB / 64);
    float rowacc = 0.f;
    f32x4 acc[4];
#pragma unroll
    for (int df = 0; df < 4; ++df) acc[df] = (f32x4){0.f, 0.f, 0.f, 0.f};

    // K staging: row kr = t>>2 (0..127), chunks (t&3)*16 + i*64 within 128B row
    const int kr = t >> 2, kcb = (t & 3) * 16;
    const int kswz = (kr & 7) << 4;
    // V staging: row vr = t>>3 (0..63), chunks (t&7)*16 + i*128 within 256B row
    const int vr = t >> 3, vcb = (t & 7) * 16;
    const int vswz = (vr & 7) << 4;

    s16x8 kreg[2], vreg[2];

    auto LOAD = [&](int j0) {   // j0 = first k-row of the 128-row pair
#pragma unroll
        for (int i = 0; i < 2; ++i) {
            kreg[i] = *(const s16x8*)((const char*)(Kbase + (size_t)(j0 + kr) * DB) +
                                      kcb + i * 64);
            vreg[i] = *(const s16x8*)((const char*)(Vbase + (size_t)vr * SB + j0) +
                                      vcb + i * 128);
        }
    };
    auto STORE = [&](int buf) {
#pragma unroll
        for (int i = 0; i < 2; ++i) {
            *(s16x8*)(&Klds[buf][0] + kr * 128 + ((kcb + i * 64) ^ kswz)) = kreg[i];
            *(s16x8*)(&Vlds[buf][0] + vr * 256 + ((vcb + i * 128) ^ vswz)) = vreg[i];
        }
    };
    // COMPUTE one 64-k tile: p = which half of the pair, mw64 = mask word
    auto COMPUTE = [&](int buf, int p, unsigned long long mw64) {
        f32x4 sc[4];
        __builtin_amdgcn_s_setprio(1);
#pragma unroll
        for (int jf = 0; jf < 4; ++jf) {
            sc[jf] = (f32x4){0.f, 0.f, 0.f, 0.f};
#pragma unroll
            for (int ks = 0; ks < 2; ++ks) {
                s16x8 kf = *(const s16x8*)(&Klds[buf][0] + (p * 64 + jf * 16 + c) * 128 +
                                           ((ks * 64 + g * 16) ^ ((c & 7) << 4)));
                sc[jf] = mfma16(kf, qf[ks], sc[jf]);
            }
        }
        __builtin_amdgcn_s_setprio(0);

        const unsigned long long mw = mw64 >> (g * 4);
        const unsigned int nib[4] = {
            (unsigned int)mw & 0xFu, (unsigned int)(mw >> 16) & 0xFu,
            (unsigned int)(mw >> 32) & 0xFu, (unsigned int)(mw >> 48) & 0xFu };

        s16x4 pf4[4];
#pragma unroll
        for (int jf = 0; jf < 4; ++jf) {
            float e[4];
#pragma unroll
            for (int r = 0; r < 4; ++r)
                e[r] = ((nib[jf] >> r) & 1u) ? 0.f : __builtin_amdgcn_exp2f(sc[jf][r]);
            rowacc += (e[0] + e[1]) + (e[2] + e[3]);
            union { unsigned int u[2]; s16x4 v; } pk;
            pk.u[0] = cvtpk(e[0], e[1]);
            pk.u[1] = cvtpk(e[2], e[3]);
            pf4[jf] = pk.v;
        }

        __builtin_amdgcn_s_setprio(1);
#pragma unroll
        for (int df = 0; df < 4; ++df) {
#pragma unroll
            for (int jf = 0; jf < 4; ++jf) {
                s16x4 vf = *(const s16x4*)(&Vlds[buf][0] + (df * 16 + c) * 256 +
                                           ((p * 128 + jf * 32 + g * 8) ^ ((c & 7) << 4)));
                acc[df] = mfma16x16(pf4[jf], vf, acc[df]);
            }
        }
        __builtin_amdgcn_s_setprio(0);
    };

    // ---- pipelined main loop over 32 pairs: one barrier per pair ----
    unsigned long long mw0 = mbits[mrowbase];
    unsigned long long mw1 = mbits[mrowbase + 1];
    LOAD(0);
    STORE(0);
    __syncthreads();
    int cur = 0;
    for (int jp = 0; jp < SB / 128 - 1; ++jp) {
        LOAD((jp + 1) * 128);                    // in flight across both COMPUTEs
        unsigned long long mwn0 = mbits[mrowbase + (jp + 1) * 2];
        unsigned long long mwn1 = mbits[mrowbase + (jp + 1) * 2 + 1];
        COMPUTE(cur, 0, mw0);
        COMPUTE(cur, 1, mw1);
        STORE(cur ^ 1);                          // consumes loads (vmcnt wait)
        __syncthreads();                         // nothing left pending
        mw0 = mwn0; mw1 = mwn1;
        cur ^= 1;
    }
    COMPUTE(cur, 0, mw0);
    COMPUTE(cur, 1, mw1);

    // total rowsum for q=c: butterfly over lane bits 4,5 (the g dimension)
    rowacc += __shfl_xor(rowacc, 16);
    rowacc += __shfl_xor(rowacc, 32);
    const float inv = 1.0f / rowacc;
    if (lane < 16) invbuf[(size_t)bh * SB + i0 + w * 16 + c] = inv;   // g==0

    float ir[4];
#pragma unroll
    for (int r = 0; r < 4; ++r) ir[r] = __shfl(inv, g * 4 + r);

#pragma unroll
    for (int df = 0; df < 4; ++df) {
#pragma unroll
        for (int r = 0; r < 4; ++r) {
            const int s_ = i0 + w * 16 + g * 4 + r;
            concat[(size_t)(b * SB + s_) * CB + h * DB + df * 16 + c] =
                (unsigned short)f2bf(acc[df][r] * ir[r]);
        }
    }
}

// ---------------------------------------------------------------------------
// Merged phase-2 kernel: z<16 -> attn-write (recompute scores, normalize,
// per-wave LDS transpose, coalesced NONTEMPORAL stores);
// z==16 -> final projection GEMM (out = concat @ wo^T + bo).
// ---------------------------------------------------------------------------
__global__ __launch_bounds__(256) void attn_final_kernel(
    const unsigned short* __restrict__ Qh, const unsigned short* __restrict__ Kh,
    const unsigned long long* __restrict__ mbits, const float* __restrict__ invbuf,
    float* __restrict__ attnO,
    const unsigned short* __restrict__ Ain, const float* __restrict__ W,
    const float* __restrict__ bias, float* __restrict__ out)
{
    if (blockIdx.z == 16) {
        // ---- final projection ----
        __shared__ __align__(16) short As[128 * 40];
        __shared__ __align__(16) short Bs[64 * 40];
        const int t = threadIdx.x;
        const int w = t >> 6, lane = t & 63, g = lane >> 4, c = lane & 15;
        const int wr = w >> 1, wc = w & 1;
        const int m0 = blockIdx.x * 128, n0 = blockIdx.y * 64;

        f32x4 acc[4][2];
#pragma unroll
        for (int i = 0; i < 4; ++i)
#pragma unroll
            for (int j = 0; j < 2; ++j) acc[i][j] = (f32x4){0.f, 0.f, 0.f, 0.f};

        for (int k0 = 0; k0 < CB; k0 += 32) {
            __syncthreads();
#pragma unroll
            for (int i = 0; i < 2; ++i) {
                int idx = t + i * 256; int r = idx >> 2, ch = idx & 3;
                *(s16x8*)&As[r * 40 + ch * 8] =
                    *(const s16x8*)(Ain + (size_t)(m0 + r) * CB + k0 + ch * 8);
            }
#pragma unroll
            for (int i = 0; i < 2; ++i) {
                int idx = t + i * 256; int r = idx >> 3, c4 = idx & 7;
                float4 v = *(const float4*)(W + (size_t)(n0 + r) * CB + k0 + c4 * 4);
                s16x4 p; p[0] = f2bf(v.x); p[1] = f2bf(v.y); p[2] = f2bf(v.z); p[3] = f2bf(v.w);
                *(s16x4*)&Bs[r * 40 + c4 * 4] = p;
            }
            __syncthreads();
            const int koff = g * 8;
            s16x8 a[4], bb[2];
#pragma unroll
            for (int mf = 0; mf < 4; ++mf)
                a[mf] = *(const s16x8*)&As[(wr * 64 + mf * 16 + c) * 40 + koff];
#pragma unroll
            for (int nf = 0; nf < 2; ++nf)
                bb[nf] = *(const s16x8*)&Bs[(wc * 32 + nf * 16 + c) * 40 + koff];
#pragma unroll
            for (int mf = 0; mf < 4; ++mf)
#pragma unroll
                for (int nf = 0; nf < 2; ++nf)
                    acc[mf][nf] = mfma16(a[mf], bb[nf], acc[mf][nf]);
        }

#pragma unroll
        for (int nf = 0; nf < 2; ++nf) {
            const int n = n0 + wc * 32 + nf * 16 + c;
            const float bv = bias[n];
#pragma unroll
            for (int mf = 0; mf < 4; ++mf) {
#pragma unroll
                for (int r = 0; r < 4; ++r) {
                    int m = m0 + wr * 64 + mf * 16 + g * 4 + r;
                    out[(size_t)m * CB + n] = acc[mf][nf][r] + bv;
                }
            }
        }
        return;
    }

    // ---- attn-write ----
    __shared__ __align__(16) float TP[4][16 * 64];   // 4 KB per wave

    const int t = threadIdx.x, w = t >> 6, lane = t & 63, g = lane >> 4, c = lane & 15;
    const int q0 = blockIdx.x * 64;
    const int ks0 = blockIdx.y * 512 + w * 128;
    const size_t bh = blockIdx.z;
    const unsigned short* Qb_ = Qh + (bh * SB + q0) * DB;
    const unsigned short* Kb_ = Kh + bh * SB * DB;
    float* aO = attnO + bh * (size_t)SB * SB;
    char* tp = (char*)&TP[w][0];

    s16x8 qf[4][2];
    float invv[4];
    size_t mrb[4];
#pragma unroll
    for (int qi = 0; qi < 4; ++qi) {
#pragma unroll
        for (int ks = 0; ks < 2; ++ks)
            qf[qi][ks] = *(const s16x8*)(Qb_ + (size_t)(qi * 16 + c) * DB + ks * 32 + g * 8);
        invv[qi] = invbuf[bh * SB + q0 + qi * 16 + c];
        mrb[qi] = (size_t)(q0 + qi * 16 + c) * (SB / 64);
    }

#pragma unroll
    for (int kc = 0; kc < 2; ++kc) {
        const int kch = ks0 + kc * 64;
        s16x8 kf[4][2];
#pragma unroll
        for (int jf = 0; jf < 4; ++jf)
#pragma unroll
            for (int ks = 0; ks < 2; ++ks)
                kf[jf][ks] = *(const s16x8*)(Kb_ + (size_t)(kch + jf * 16 + c) * DB + ks * 32 + g * 8);

#pragma unroll
        for (int qi = 0; qi < 4; ++qi) {
            f32x4 sc[4];
#pragma unroll
            for (int jf = 0; jf < 4; ++jf) {
                sc[jf] = (f32x4){0.f, 0.f, 0.f, 0.f};
#pragma unroll
                for (int ks = 0; ks < 2; ++ks)
                    sc[jf] = mfma16(kf[jf][ks], qf[qi][ks], sc[jf]);
            }
            unsigned long long mw = mbits[mrb[qi] + (kch >> 6)] >> (g * 4);
            const unsigned int nib[4] = {
                (unsigned int)mw & 0xFu, (unsigned int)(mw >> 16) & 0xFu,
                (unsigned int)(mw >> 32) & 0xFu, (unsigned int)(mw >> 48) & 0xFu };
            const float iv = invv[qi];

            // stage normalized tile into per-wave LDS: TP[q=c][k], swizzled
#pragma unroll
            for (int jf = 0; jf < 4; ++jf) {
                f32x4 o;
#pragma unroll
                for (int r = 0; r < 4; ++r)
                    o[r] = ((nib[jf] >> r) & 1u) ? 0.f : __builtin_amdgcn_exp2f(sc[jf][r]) * iv;
                *(f32x4*)(tp + c * 256 + ((jf * 64 + g * 16) ^ (c << 4))) = o;
            }

            // coalesced writeback: inst i covers rows i*4+g, 256B contiguous/row
            const size_t gbase = (size_t)(q0 + qi * 16) * SB + kch;
#pragma unroll
            for (int i = 0; i < 4; ++i) {
                const int rr = i * 4 + g;
                f32x4 vv = *(const f32x4*)(tp + rr * 256 + ((c * 16) ^ (rr << 4)));
                __builtin_nontemporal_store(vv, (f32x4*)(aO + gbase + (size_t)rr * SB + c * 4));
            }
        }
    }
}

extern "C" void kernel_launch(void* const* d_in, const int* in_sizes, int n_in,
                              void* d_out, int out_size, void* d_ws, size_t ws_size,
                              hipStream_t stream) {
    const float* q    = (const float*)d_in[0];
    const float* k    = (const float*)d_in[1];
    const float* v    = (const float*)d_in[2];
    const float* mask = (const float*)d_in[3];
    const float* wq   = (const float*)d_in[4];
    const float* bq   = (const float*)d_in[5];
    const float* wk   = (const float*)d_in[6];
    const float* bk   = (const float*)d_in[7];
    const float* wv   = (const float*)d_in[8];
    const float* bv   = (const float*)d_in[9];
    const float* wo   = (const float*)d_in[10];
    const float* bo   = (const float*)d_in[11];

    const size_t NE = (size_t)BB * HB * SB * DB;  // 4,194,304 elements
    unsigned short* Qh     = (unsigned short*)d_ws;
    unsigned short* Kh     = Qh + NE;
    unsigned short* Vt     = Kh + NE;
    unsigned short* concat = Vt + NE;
    unsigned long long* mbits = (unsigned long long*)((char*)d_ws + 4 * NE * sizeof(unsigned short));
    float* invbuf = (float*)((char*)d_ws + 4 * NE * sizeof(unsigned short) + (size_t)SB * SB / 8);

    float* outp  = (float*)d_out;
    float* attnp = outp + (size_t)BB * SB * CB;

    // z: 0..2 = Q/K/V projection, 3..130 = mask bitmask chunks (128 slices)
    qkv_mask_kernel<<<dim3(64, 8, 131), 256, 0, stream>>>(
        q, k, v, wq, wk, wv, bq, bk, bv, Qh, Kh, Vt, mask, mbits);
    flash_kernel<<<dim3(512, 1, 1), 512, 0, stream>>>(Qh, Kh, Vt, mbits, concat, invbuf);
    // z: 0..15 = attn-write per (b,h); z==16 = final projection
    attn_final_kernel<<<dim3(SB / 64, 8, HB * BB + 1), 256, 0, stream>>>(
        Qh, Kh, mbits, invbuf, attnp, concat, wo, bo, outp);
}

// Round 15
// 401.887 us; speedup vs baseline: 1.0325x; 1.0325x over previous
//
#include <hip/hip_runtime.h>
#include <hip/hip_bf16.h>
#include <cstdint>

// Problem constants: B=2, S=4096, C=512, H=8, D=64
#define SB 4096
#define CB 512
#define HB 8
#define DB 64
#define BB 2

// 0.125 * log2(e): folded into Q projection so softmax uses exp2 directly.
#define QSCALE 0.18033688011112042f

typedef __attribute__((ext_vector_type(8))) short s16x8;
typedef __attribute__((ext_vector_type(4))) short s16x4;
typedef __attribute__((ext_vector_type(4))) float f32x4;

__device__ __forceinline__ short f2bf(float f) {
    union { float f; unsigned int u; } v; v.f = f;
    unsigned int r = v.u + 0x7fffu + ((v.u >> 16) & 1u);
    return (short)(r >> 16);
}

// pack two f32 -> bf16 pair (S0 in low half), RNE
__device__ __forceinline__ unsigned int cvtpk(float lo, float hi) {
    unsigned int r;
    asm("v_cvt_pk_bf16_f32 %0, %1, %2" : "=v"(r) : "v"(lo), "v"(hi));
    return r;
}

__device__ __forceinline__ f32x4 mfma16(s16x8 a, s16x8 b, f32x4 c) {
    return __builtin_amdgcn_mfma_f32_16x16x32_bf16(a, b, c, 0, 0, 0);
}

// K=16 bf16 MFMA via inline asm (A/B: 4 bf16 per lane, chunk (lane>>4)*4)
__device__ __forceinline__ f32x4 mfma16x16(s16x4 a, s16x4 b, f32x4 c) {
    asm("v_mfma_f32_16x16x16_bf16 %0, %1, %2, %0" : "+v"(c) : "v"(a), "v"(b));
    return c;
}

// ---------------------------------------------------------------------------
// QKV projection + mask-bitmask (one launch):
// z==0: Q -> bf16 [b,h,s,d] scaled by QSCALE
// z==1: K -> bf16 [b,h,s,d]
// z==2: V -> bf16 [b,h,d,s]  (transposed)
// z>=3: mask -> bitmask chunks (overlaps the proj GEMM; independent work)
// ---------------------------------------------------------------------------
__global__ __launch_bounds__(256) void qkv_mask_kernel(
    const float* __restrict__ q, const float* __restrict__ k, const float* __restrict__ v,
    const float* __restrict__ wq, const float* __restrict__ wk, const float* __restrict__ wv,
    const float* __restrict__ bq, const float* __restrict__ bk, const float* __restrict__ bv,
    unsigned short* __restrict__ Qh, unsigned short* __restrict__ Kh,
    unsigned short* __restrict__ Vt,
    const float* __restrict__ mask, unsigned long long* __restrict__ bits)
{
    const int z = blockIdx.z;
    if (z >= 3) {
        size_t idx = (((size_t)(z - 3) * 512) + blockIdx.y * 64 + blockIdx.x) * 256
                     + threadIdx.x;
        float mv = mask[idx];
        unsigned long long bmask = __ballot(mv != 0.0f);
        if ((threadIdx.x & 63) == 0) bits[idx >> 6] = bmask;
        return;
    }

    const float* X = (z == 0) ? q : (z == 1) ? k : v;
    const float* W = (z == 0) ? wq : (z == 1) ? wk : wv;
    const float* bias = (z == 0) ? bq : (z == 1) ? bk : bv;
    unsigned short* dst = (z == 0) ? Qh : (z == 1) ? Kh : Vt;
    const float oscale = (z == 0) ? QSCALE : 1.0f;
    const int which = (z == 2) ? 2 : 0;

    __shared__ __align__(16) short As[128 * 40];
    __shared__ __align__(16) short Bs[64 * 40];
    const int t = threadIdx.x;
    const int w = t >> 6, lane = t & 63, g = lane >> 4, c = lane & 15;
    const int wr = w >> 1, wc = w & 1;
    const int m0 = blockIdx.x * 128, n0 = blockIdx.y * 64;

    f32x4 acc[4][2];
#pragma unroll
    for (int i = 0; i < 4; ++i)
#pragma unroll
        for (int j = 0; j < 2; ++j) acc[i][j] = (f32x4){0.f, 0.f, 0.f, 0.f};

    for (int k0 = 0; k0 < CB; k0 += 32) {
        __syncthreads();
#pragma unroll
        for (int i = 0; i < 4; ++i) {
            int idx = t + i * 256; int r = idx >> 3, c4 = idx & 7;
            float4 vv = *(const float4*)(X + (size_t)(m0 + r) * CB + k0 + c4 * 4);
            s16x4 p; p[0] = f2bf(vv.x); p[1] = f2bf(vv.y); p[2] = f2bf(vv.z); p[3] = f2bf(vv.w);
            *(s16x4*)&As[r * 40 + c4 * 4] = p;
        }
#pragma unroll
        for (int i = 0; i < 2; ++i) {
            int idx = t + i * 256; int r = idx >> 3, c4 = idx & 7;
            float4 vv = *(const float4*)(W + (size_t)(n0 + r) * CB + k0 + c4 * 4);
            s16x4 p; p[0] = f2bf(vv.x); p[1] = f2bf(vv.y); p[2] = f2bf(vv.z); p[3] = f2bf(vv.w);
            *(s16x4*)&Bs[r * 40 + c4 * 4] = p;
        }
        __syncthreads();
        const int koff = g * 8;
        s16x8 a[4], bb[2];
#pragma unroll
        for (int mf = 0; mf < 4; ++mf)
            a[mf] = *(const s16x8*)&As[(wr * 64 + mf * 16 + c) * 40 + koff];
#pragma unroll
        for (int nf = 0; nf < 2; ++nf)
            bb[nf] = *(const s16x8*)&Bs[(wc * 32 + nf * 16 + c) * 40 + koff];
#pragma unroll
        for (int mf = 0; mf < 4; ++mf)
#pragma unroll
            for (int nf = 0; nf < 2; ++nf)
                acc[mf][nf] = mfma16(a[mf], bb[nf], acc[mf][nf]);
    }

#pragma unroll
    for (int nf = 0; nf < 2; ++nf) {
        const int n = n0 + wc * 32 + nf * 16 + c;
        const float bv2 = bias[n];
        const int h = n >> 6, d = n & 63;
#pragma unroll
        for (int mf = 0; mf < 4; ++mf) {
#pragma unroll
            for (int r = 0; r < 4; ++r) {
                int m = m0 + wr * 64 + mf * 16 + g * 4 + r;
                float val = (acc[mf][nf][r] + bv2) * oscale;
                int b = m >> 12, s = m & (SB - 1);
                size_t off;
                if (which == 0) off = (((size_t)(b * HB + h)) * SB + s) * DB + d;
                else            off = (((size_t)(b * HB + h)) * DB + d) * SB + s;
                dst[off] = (unsigned short)f2bf(val);
            }
        }
    }
}

// ---------------------------------------------------------------------------
// Flash kernel (phase 1) — R13 config (proven best): 8 waves / 128 q-rows per
// block, 512 blocks, XCD-aware map (bh {2*xcd,2*xcd+1} per XCD, L2-resident).
//   loop: LOAD(t+1) -> COMPUTE(t,cur) -> STORE(cur^1) -> barrier
// Swapped-operand QK (out[k][q]); per-lane rowsum; PV via 16x16x16 MFMA on
// packed score regs. K/V LDS tiles XOR-swizzled (byte ^= (row&7)<<4).
// Q is pre-scaled by 0.125*log2(e), so e = exp2(QK) directly.
// ---------------------------------------------------------------------------
__global__ __launch_bounds__(512) void flash_kernel(
    const unsigned short* __restrict__ Qh, const unsigned short* __restrict__ Kh,
    const unsigned short* __restrict__ Vt, const unsigned long long* __restrict__ mbits,
    unsigned short* __restrict__ concat, float* __restrict__ invbuf)
{
    __shared__ __align__(16) short Klds[2][64 * 64];  // 2 x 8 KB, swizzled
    __shared__ __align__(16) short Vlds[2][64 * 64];

    const int t = threadIdx.x, w = t >> 6, lane = t & 63, g = lane >> 4, c = lane & 15;
    // XCD-aware map: 512 blocks; xcd = bid&7 owns bh {2*xcd, 2*xcd+1}.
    const int bid = blockIdx.x;
    const int xcd = bid & 7, idx = bid >> 3;          // idx in [0,64)
    const int bh = xcd * 2 + (idx >> 5);              // 2 bh per xcd
    const int qb = idx & 31;                          // 32 q-blocks per bh
    const int b = bh >> 3, h = bh & 7;
    const int i0 = qb * 128;

    const unsigned short* Qbase = Qh + ((size_t)bh * SB + i0 + w * 16) * DB;
    const unsigned short* Kbase = Kh + (size_t)bh * SB * DB;
    const unsigned short* Vbase = Vt + (size_t)bh * DB * SB;

    // Q fragments (B-operand): lane c holds Q row (i0+w*16+c), chunk ks*32+g*8
    s16x8 qf[2];
#pragma unroll
    for (int ks = 0; ks < 2; ++ks)
        qf[ks] = *(const s16x8*)(Qbase + (size_t)c * DB + ks * 32 + g * 8);

    const int qrow = i0 + w * 16 + c;
    const size_t mrowbase = (size_t)qrow * (SB / 64);
    float rowacc = 0.f;
    f32x4 acc[4];
#pragma unroll
    for (int df = 0; df < 4; ++df) acc[df] = (f32x4){0.f, 0.f, 0.f, 0.f};

    // staging: 512 threads, one 16B K-chunk + one 16B V-chunk each per tile
    const int sr = t >> 3;                 // row 0..63
    const int colb = (t & 7) * 16;         // byte offset within 128B row
    const int swz = (sr & 7) << 4;

    s16x8 kreg, vreg;                      // staging registers

    auto LOAD = [&](int j0) {
        kreg = *(const s16x8*)((const char*)(Kbase + (size_t)(j0 + sr) * DB) + colb);
        vreg = *(const s16x8*)((const char*)(Vbase + (size_t)sr * SB + j0) + colb);
    };
    auto STORE = [&](int buf) {
        *(s16x8*)((char*)&Klds[buf][0] + sr * 128 + (colb ^ swz)) = kreg;
        *(s16x8*)((char*)&Vlds[buf][0] + sr * 128 + (colb ^ swz)) = vreg;
    };
    auto COMPUTE = [&](int buf, unsigned long long mw64) {
        // QK^T swapped: sc[jf] lane(c,g) reg r = score[k=j0+jf*16+g*4+r][q=qrow]
        f32x4 sc[4];
        __builtin_amdgcn_s_setprio(1);
#pragma unroll
        for (int jf = 0; jf < 4; ++jf) {
            sc[jf] = (f32x4){0.f, 0.f, 0.f, 0.f};
#pragma unroll
            for (int ks = 0; ks < 2; ++ks) {
                s16x8 kf = *(const s16x8*)((char*)&Klds[buf][0] + (jf * 16 + c) * 128 +
                                           ((ks * 64 + g * 16) ^ ((c & 7) << 4)));
                sc[jf] = mfma16(kf, qf[ks], sc[jf]);
            }
        }
        __builtin_amdgcn_s_setprio(0);

        const unsigned long long mw = mw64 >> (g * 4);
        const unsigned int nib[4] = {
            (unsigned int)mw & 0xFu, (unsigned int)(mw >> 16) & 0xFu,
            (unsigned int)(mw >> 32) & 0xFu, (unsigned int)(mw >> 48) & 0xFu };

        s16x4 pf4[4];
#pragma unroll
        for (int jf = 0; jf < 4; ++jf) {
            float e[4];
#pragma unroll
            for (int r = 0; r < 4; ++r)
                e[r] = ((nib[jf] >> r) & 1u) ? 0.f : __builtin_amdgcn_exp2f(sc[jf][r]);
            rowacc += (e[0] + e[1]) + (e[2] + e[3]);
            union { unsigned int u[2]; s16x4 v; } pk;
            pk.u[0] = cvtpk(e[0], e[1]);
            pk.u[1] = cvtpk(e[2], e[3]);
            pf4[jf] = pk.v;
        }

        // PV: out[q][d] += P[q][k] V^T[d][k], 16x16x16; pf4 is already A-layout.
        __builtin_amdgcn_s_setprio(1);
#pragma unroll
        for (int df = 0; df < 4; ++df) {
#pragma unroll
            for (int jf = 0; jf < 4; ++jf) {
                s16x4 vf = *(const s16x4*)((char*)&Vlds[buf][0] + (df * 16 + c) * 128 +
                                           ((jf * 32 + g * 8) ^ ((c & 7) << 4)));
                acc[df] = mfma16x16(pf4[jf], vf, acc[df]);
            }
        }
        __builtin_amdgcn_s_setprio(0);
    };

    // ---- pipelined main loop: LOAD -> COMPUTE -> STORE -> barrier ----
    unsigned long long mwcur = mbits[mrowbase];
    LOAD(0);
    STORE(0);
    __syncthreads();
    int cur = 0;
    for (int jt = 0; jt < SB / 64 - 1; ++jt) {
        LOAD((jt + 1) * 64);                     // in flight across COMPUTE
        unsigned long long mwnext = mbits[mrowbase + jt + 1];
        COMPUTE(cur, mwcur);
        STORE(cur ^ 1);                          // consumes loads (vmcnt wait)
        __syncthreads();                         // nothing left pending
        mwcur = mwnext;
        cur ^= 1;
    }
    COMPUTE(cur, mwcur);

    // total rowsum for q=c: butterfly over lane bits 4,5 (the g dimension)
    rowacc += __shfl_xor(rowacc, 16);
    rowacc += __shfl_xor(rowacc, 32);
    const float inv = 1.0f / rowacc;
    if (lane < 16) invbuf[(size_t)bh * SB + i0 + w * 16 + c] = inv;   // g==0

    float ir[4];
#pragma unroll
    for (int r = 0; r < 4; ++r) ir[r] = __shfl(inv, g * 4 + r);

#pragma unroll
    for (int df = 0; df < 4; ++df) {
#pragma unroll
        for (int r = 0; r < 4; ++r) {
            const int s_ = i0 + w * 16 + g * 4 + r;
            concat[(size_t)(b * SB + s_) * CB + h * DB + df * 16 + c] =
                (unsigned short)f2bf(acc[df][r] * ir[r]);
        }
    }
}

// ---------------------------------------------------------------------------
// Merged phase-2 kernel, 1-D grid with XCD-aware bh chunking:
// bid < 8192: attn-write. xcd = bid&7 owns bh {2*xcd, 2*xcd+1} -> per-XCD K
//   working set 2 MB (L2-resident) instead of 16 streams via L3.
//   Within bh: 64 q-blocks x 8 k-chunks. Recompute scores, normalize with
//   invbuf, per-wave LDS transpose, coalesced nontemporal 256B stores.
// bid >= 8192: final projection GEMM (dispatches last -> tail fill).
// ---------------------------------------------------------------------------
__global__ __launch_bounds__(256) void attn_final_kernel(
    const unsigned short* __restrict__ Qh, const unsigned short* __restrict__ Kh,
    const unsigned long long* __restrict__ mbits, const float* __restrict__ invbuf,
    float* __restrict__ attnO,
    const unsigned short* __restrict__ Ain, const float* __restrict__ W,
    const float* __restrict__ bias, float* __restrict__ out)
{
    const int bid = blockIdx.x;
    if (bid >= 8192) {
        // ---- final projection: fid -> (m0, n0) over 64 x 8 tiles ----
        const int fid = bid - 8192;
        __shared__ __align__(16) short As[128 * 40];
        __shared__ __align__(16) short Bs[64 * 40];
        const int t = threadIdx.x;
        const int w = t >> 6, lane = t & 63, g = lane >> 4, c = lane & 15;
        const int wr = w >> 1, wc = w & 1;
        const int m0 = (fid >> 3) * 128, n0 = (fid & 7) * 64;

        f32x4 acc[4][2];
#pragma unroll
        for (int i = 0; i < 4; ++i)
#pragma unroll
            for (int j = 0; j < 2; ++j) acc[i][j] = (f32x4){0.f, 0.f, 0.f, 0.f};

        for (int k0 = 0; k0 < CB; k0 += 32) {
            __syncthreads();
#pragma unroll
            for (int i = 0; i < 2; ++i) {
                int idx = t + i * 256; int r = idx >> 2, ch = idx & 3;
                *(s16x8*)&As[r * 40 + ch * 8] =
                    *(const s16x8*)(Ain + (size_t)(m0 + r) * CB + k0 + ch * 8);
            }
#pragma unroll
            for (int i = 0; i < 2; ++i) {
                int idx = t + i * 256; int r = idx >> 3, c4 = idx & 7;
                float4 v = *(const float4*)(W + (size_t)(n0 + r) * CB + k0 + c4 * 4);
                s16x4 p; p[0] = f2bf(v.x); p[1] = f2bf(v.y); p[2] = f2bf(v.z); p[3] = f2bf(v.w);
                *(s16x4*)&Bs[r * 40 + c4 * 4] = p;
            }
            __syncthreads();
            const int koff = g * 8;
            s16x8 a[4], bb[2];
#pragma unroll
            for (int mf = 0; mf < 4; ++mf)
                a[mf] = *(const s16x8*)&As[(wr * 64 + mf * 16 + c) * 40 + koff];
#pragma unroll
            for (int nf = 0; nf < 2; ++nf)
                bb[nf] = *(const s16x8*)&Bs[(wc * 32 + nf * 16 + c) * 40 + koff];
#pragma unroll
            for (int mf = 0; mf < 4; ++mf)
#pragma unroll
                for (int nf = 0; nf < 2; ++nf)
                    acc[mf][nf] = mfma16(a[mf], bb[nf], acc[mf][nf]);
        }

#pragma unroll
        for (int nf = 0; nf < 2; ++nf) {
            const int n = n0 + wc * 32 + nf * 16 + c;
            const float bv = bias[n];
#pragma unroll
            for (int mf = 0; mf < 4; ++mf) {
#pragma unroll
                for (int r = 0; r < 4; ++r) {
                    int m = m0 + wr * 64 + mf * 16 + g * 4 + r;
                    out[(size_t)m * CB + n] = acc[mf][nf][r] + bv;
                }
            }
        }
        return;
    }

    // ---- attn-write, XCD-chunked ----
    __shared__ __align__(16) float TP[4][16 * 64];   // 4 KB per wave

    const int t = threadIdx.x, w = t >> 6, lane = t & 63, g = lane >> 4, c = lane & 15;
    const int xcd = bid & 7, rest = bid >> 3;        // rest in [0,1024)
    const size_t bh = (size_t)(xcd * 2 + (rest >> 9));  // 2 bh per xcd
    const int sub = rest & 511;                      // 64 q-blocks x 8 k-chunks
    const int q0 = (sub >> 3) * 64;
    const int ks0 = (sub & 7) * 512 + w * 128;

    const unsigned short* Qb_ = Qh + (bh * SB + q0) * DB;
    const unsigned short* Kb_ = Kh + bh * SB * DB;
    float* aO = attnO + bh * (size_t)SB * SB;
    char* tp = (char*)&TP[w][0];

    s16x8 qf[4][2];
    float invv[4];
    size_t mrb[4];
#pragma unroll
    for (int qi = 0; qi < 4; ++qi) {
#pragma unroll
        for (int ks = 0; ks < 2; ++ks)
            qf[qi][ks] = *(const s16x8*)(Qb_ + (size_t)(qi * 16 + c) * DB + ks * 32 + g * 8);
        invv[qi] = invbuf[bh * SB + q0 + qi * 16 + c];
        mrb[qi] = (size_t)(q0 + qi * 16 + c) * (SB / 64);
    }

#pragma unroll
    for (int kc = 0; kc < 2; ++kc) {
        const int kch = ks0 + kc * 64;
        s16x8 kf[4][2];
#pragma unroll
        for (int jf = 0; jf < 4; ++jf)
#pragma unroll
            for (int ks = 0; ks < 2; ++ks)
                kf[jf][ks] = *(const s16x8*)(Kb_ + (size_t)(kch + jf * 16 + c) * DB + ks * 32 + g * 8);

#pragma unroll
        for (int qi = 0; qi < 4; ++qi) {
            f32x4 sc[4];
#pragma unroll
            for (int jf = 0; jf < 4; ++jf) {
                sc[jf] = (f32x4){0.f, 0.f, 0.f, 0.f};
#pragma unroll
                for (int ks = 0; ks < 2; ++ks)
                    sc[jf] = mfma16(kf[jf][ks], qf[qi][ks], sc[jf]);
            }
            unsigned long long mw = mbits[mrb[qi] + (kch >> 6)] >> (g * 4);
            const unsigned int nib[4] = {
                (unsigned int)mw & 0xFu, (unsigned int)(mw >> 16) & 0xFu,
                (unsigned int)(mw >> 32) & 0xFu, (unsigned int)(mw >> 48) & 0xFu };
            const float iv = invv[qi];

            // stage normalized tile into per-wave LDS: TP[q=c][k], swizzled
#pragma unroll
            for (int jf = 0; jf < 4; ++jf) {
                f32x4 o;
#pragma unroll
                for (int r = 0; r < 4; ++r)
                    o[r] = ((nib[jf] >> r) & 1u) ? 0.f : __builtin_amdgcn_exp2f(sc[jf][r]) * iv;
                *(f32x4*)(tp + c * 256 + ((jf * 64 + g * 16) ^ (c << 4))) = o;
            }

            // coalesced writeback: inst i covers rows i*4+g, 256B contiguous/row
            const size_t gbase = (size_t)(q0 + qi * 16) * SB + kch;
#pragma unroll
            for (int i = 0; i < 4; ++i) {
                const int rr = i * 4 + g;
                f32x4 vv = *(const f32x4*)(tp + rr * 256 + ((c * 16) ^ (rr << 4)));
                __builtin_nontemporal_store(vv, (f32x4*)(aO + gbase + (size_t)rr * SB + c * 4));
            }
        }
    }
}

extern "C" void kernel_launch(void* const* d_in, const int* in_sizes, int n_in,
                              void* d_out, int out_size, void* d_ws, size_t ws_size,
                              hipStream_t stream) {
    const float* q    = (const float*)d_in[0];
    const float* k    = (const float*)d_in[1];
    const float* v    = (const float*)d_in[2];
    const float* mask = (const float*)d_in[3];
    const float* wq   = (const float*)d_in[4];
    const float* bq   = (const float*)d_in[5];
    const float* wk   = (const float*)d_in[6];
    const float* bk   = (const float*)d_in[7];
    const float* wv   = (const float*)d_in[8];
    const float* bv   = (const float*)d_in[9];
    const float* wo   = (const float*)d_in[10];
    const float* bo   = (const float*)d_in[11];

    const size_t NE = (size_t)BB * HB * SB * DB;  // 4,194,304 elements
    unsigned short* Qh     = (unsigned short*)d_ws;
    unsigned short* Kh     = Qh + NE;
    unsigned short* Vt     = Kh + NE;
    unsigned short* concat = Vt + NE;
    unsigned long long* mbits = (unsigned long long*)((char*)d_ws + 4 * NE * sizeof(unsigned short));
    float* invbuf = (float*)((char*)d_ws + 4 * NE * sizeof(unsigned short) + (size_t)SB * SB / 8);

    float* outp  = (float*)d_out;
    float* attnp = outp + (size_t)BB * SB * CB;

    // z: 0..2 = Q/K/V projection, 3..130 = mask bitmask chunks (128 slices)
    qkv_mask_kernel<<<dim3(64, 8, 131), 256, 0, stream>>>(
        q, k, v, wq, wk, wv, bq, bk, bv, Qh, Kh, Vt, mask, mbits);
    flash_kernel<<<dim3(512, 1, 1), 512, 0, stream>>>(Qh, Kh, Vt, mbits, concat, invbuf);
    // 1-D: bid 0..8191 = attn-write (XCD-chunked), 8192..8703 = final proj
    attn_final_kernel<<<dim3(8704, 1, 1), 256, 0, stream>>>(
        Qh, Kh, mbits, invbuf, attnp, concat, wo, bo, outp);
}

// Round 16
// 396.879 us; speedup vs baseline: 1.0455x; 1.0126x over previous
//
#include <hip/hip_runtime.h>
#include <hip/hip_bf16.h>
#include <cstdint>

// Problem constants: B=2, S=4096, C=512, H=8, D=64
#define SB 4096
#define CB 512
#define HB 8
#define DB 64
#define BB 2

// 0.125 * log2(e): folded into Q projection so softmax uses exp2 directly.
#define QSCALE 0.18033688011112042f

typedef __attribute__((ext_vector_type(8))) short s16x8;
typedef __attribute__((ext_vector_type(4))) short s16x4;
typedef __attribute__((ext_vector_type(4))) float f32x4;

__device__ __forceinline__ short f2bf(float f) {
    union { float f; unsigned int u; } v; v.f = f;
    unsigned int r = v.u + 0x7fffu + ((v.u >> 16) & 1u);
    return (short)(r >> 16);
}

// pack two f32 -> bf16 pair (S0 in low half), RNE
__device__ __forceinline__ unsigned int cvtpk(float lo, float hi) {
    unsigned int r;
    asm("v_cvt_pk_bf16_f32 %0, %1, %2" : "=v"(r) : "v"(lo), "v"(hi));
    return r;
}

__device__ __forceinline__ f32x4 mfma16(s16x8 a, s16x8 b, f32x4 c) {
    return __builtin_amdgcn_mfma_f32_16x16x32_bf16(a, b, c, 0, 0, 0);
}

// K=16 bf16 MFMA via inline asm (A/B: 4 bf16 per lane, chunk (lane>>4)*4)
__device__ __forceinline__ f32x4 mfma16x16(s16x4 a, s16x4 b, f32x4 c) {
    asm("v_mfma_f32_16x16x16_bf16 %0, %1, %2, %0" : "+v"(c) : "v"(a), "v"(b));
    return c;
}

// ---------------------------------------------------------------------------
// QKV projection + mask-bitmask (one launch).
// Projection now uses a 128x128 tile (guide ladder m92->m93: 2x arithmetic
// intensity per LDS byte): 4 waves 2x2, each 64x64 = 4x4 fragments, 32 MFMA
// per K-step. Grid (64, 4, 3 + 256 mask slices).
// z==0: Q -> bf16 [b,h,s,d] scaled by QSCALE
// z==1: K -> bf16 [b,h,s,d]
// z==2: V -> bf16 [b,h,d,s]  (transposed)
// z>=3: mask -> bitmask chunks (overlaps the proj GEMM; independent work)
// ---------------------------------------------------------------------------
__global__ __launch_bounds__(256) void qkv_mask_kernel(
    const float* __restrict__ q, const float* __restrict__ k, const float* __restrict__ v,
    const float* __restrict__ wq, const float* __restrict__ wk, const float* __restrict__ wv,
    const float* __restrict__ bq, const float* __restrict__ bk, const float* __restrict__ bv,
    unsigned short* __restrict__ Qh, unsigned short* __restrict__ Kh,
    unsigned short* __restrict__ Vt,
    const float* __restrict__ mask, unsigned long long* __restrict__ bits)
{
    const int z = blockIdx.z;
    if (z >= 3) {
        // mask -> bitmask: 256 slices x (64x4 blocks) x 256 threads = 16.7M elems
        size_t idx = (((size_t)(z - 3) * 256) + blockIdx.y * 64 + blockIdx.x) * 256
                     + threadIdx.x;
        float mv = mask[idx];
        unsigned long long bmask = __ballot(mv != 0.0f);
        if ((threadIdx.x & 63) == 0) bits[idx >> 6] = bmask;
        return;
    }

    const float* X = (z == 0) ? q : (z == 1) ? k : v;
    const float* W = (z == 0) ? wq : (z == 1) ? wk : wv;
    const float* bias = (z == 0) ? bq : (z == 1) ? bk : bv;
    unsigned short* dst = (z == 0) ? Qh : (z == 1) ? Kh : Vt;
    const float oscale = (z == 0) ? QSCALE : 1.0f;
    const int which = (z == 2) ? 2 : 0;

    __shared__ __align__(16) short As[128 * 40];
    __shared__ __align__(16) short Bs[128 * 40];
    const int t = threadIdx.x;
    const int w = t >> 6, lane = t & 63, g = lane >> 4, c = lane & 15;
    const int wr = w >> 1, wc = w & 1;
    const int m0 = blockIdx.x * 128, n0 = blockIdx.y * 128;

    f32x4 acc[4][4];
#pragma unroll
    for (int i = 0; i < 4; ++i)
#pragma unroll
        for (int j = 0; j < 4; ++j) acc[i][j] = (f32x4){0.f, 0.f, 0.f, 0.f};

    for (int k0 = 0; k0 < CB; k0 += 32) {
        __syncthreads();
#pragma unroll
        for (int i = 0; i < 4; ++i) {
            int idx = t + i * 256; int r = idx >> 3, c4 = idx & 7;
            float4 vv = *(const float4*)(X + (size_t)(m0 + r) * CB + k0 + c4 * 4);
            s16x4 p; p[0] = f2bf(vv.x); p[1] = f2bf(vv.y); p[2] = f2bf(vv.z); p[3] = f2bf(vv.w);
            *(s16x4*)&As[r * 40 + c4 * 4] = p;
        }
#pragma unroll
        for (int i = 0; i < 4; ++i) {
            int idx = t + i * 256; int r = idx >> 3, c4 = idx & 7;
            float4 vv = *(const float4*)(W + (size_t)(n0 + r) * CB + k0 + c4 * 4);
            s16x4 p; p[0] = f2bf(vv.x); p[1] = f2bf(vv.y); p[2] = f2bf(vv.z); p[3] = f2bf(vv.w);
            *(s16x4*)&Bs[r * 40 + c4 * 4] = p;
        }
        __syncthreads();
        const int koff = g * 8;
        s16x8 a[4], bb[4];
#pragma unroll
        for (int mf = 0; mf < 4; ++mf)
            a[mf] = *(const s16x8*)&As[(wr * 64 + mf * 16 + c) * 40 + koff];
#pragma unroll
        for (int nf = 0; nf < 4; ++nf)
            bb[nf] = *(const s16x8*)&Bs[(wc * 64 + nf * 16 + c) * 40 + koff];
#pragma unroll
        for (int mf = 0; mf < 4; ++mf)
#pragma unroll
            for (int nf = 0; nf < 4; ++nf)
                acc[mf][nf] = mfma16(a[mf], bb[nf], acc[mf][nf]);
    }

#pragma unroll
    for (int nf = 0; nf < 4; ++nf) {
        const int n = n0 + wc * 64 + nf * 16 + c;
        const float bv2 = bias[n];
        const int h = n >> 6, d = n & 63;
#pragma unroll
        for (int mf = 0; mf < 4; ++mf) {
#pragma unroll
            for (int r = 0; r < 4; ++r) {
                int m = m0 + wr * 64 + mf * 16 + g * 4 + r;
                float val = (acc[mf][nf][r] + bv2) * oscale;
                int b = m >> 12, s = m & (SB - 1);
                size_t off;
                if (which == 0) off = (((size_t)(b * HB + h)) * SB + s) * DB + d;
                else            off = (((size_t)(b * HB + h)) * DB + d) * SB + s;
                dst[off] = (unsigned short)f2bf(val);
            }
        }
    }
}

// ---------------------------------------------------------------------------
// Flash kernel (phase 1) — R13 config (proven best): 8 waves / 128 q-rows per
// block, 512 blocks, XCD-aware map (bh {2*xcd,2*xcd+1} per XCD, L2-resident).
//   loop: LOAD(t+1) -> COMPUTE(t,cur) -> STORE(cur^1) -> barrier
// Swapped-operand QK (out[k][q]); per-lane rowsum; PV via 16x16x16 MFMA on
// packed score regs. K/V LDS tiles XOR-swizzled (byte ^= (row&7)<<4).
// Q is pre-scaled by 0.125*log2(e), so e = exp2(QK) directly.
// ---------------------------------------------------------------------------
__global__ __launch_bounds__(512) void flash_kernel(
    const unsigned short* __restrict__ Qh, const unsigned short* __restrict__ Kh,
    const unsigned short* __restrict__ Vt, const unsigned long long* __restrict__ mbits,
    unsigned short* __restrict__ concat, float* __restrict__ invbuf)
{
    __shared__ __align__(16) short Klds[2][64 * 64];  // 2 x 8 KB, swizzled
    __shared__ __align__(16) short Vlds[2][64 * 64];

    const int t = threadIdx.x, w = t >> 6, lane = t & 63, g = lane >> 4, c = lane & 15;
    // XCD-aware map: 512 blocks; xcd = bid&7 owns bh {2*xcd, 2*xcd+1}.
    const int bid = blockIdx.x;
    const int xcd = bid & 7, idx = bid >> 3;          // idx in [0,64)
    const int bh = xcd * 2 + (idx >> 5);              // 2 bh per xcd
    const int qb = idx & 31;                          // 32 q-blocks per bh
    const int b = bh >> 3, h = bh & 7;
    const int i0 = qb * 128;

    const unsigned short* Qbase = Qh + ((size_t)bh * SB + i0 + w * 16) * DB;
    const unsigned short* Kbase = Kh + (size_t)bh * SB * DB;
    const unsigned short* Vbase = Vt + (size_t)bh * DB * SB;

    // Q fragments (B-operand): lane c holds Q row (i0+w*16+c), chunk ks*32+g*8
    s16x8 qf[2];
#pragma unroll
    for (int ks = 0; ks < 2; ++ks)
        qf[ks] = *(const s16x8*)(Qbase + (size_t)c * DB + ks * 32 + g * 8);

    const int qrow = i0 + w * 16 + c;
    const size_t mrowbase = (size_t)qrow * (SB / 64);
    float rowacc = 0.f;
    f32x4 acc[4];
#pragma unroll
    for (int df = 0; df < 4; ++df) acc[df] = (f32x4){0.f, 0.f, 0.f, 0.f};

    // staging: 512 threads, one 16B K-chunk + one 16B V-chunk each per tile
    const int sr = t >> 3;                 // row 0..63
    const int colb = (t & 7) * 16;         // byte offset within 128B row
    const int swz = (sr & 7) << 4;

    s16x8 kreg, vreg;                      // staging registers

    auto LOAD = [&](int j0) {
        kreg = *(const s16x8*)((const char*)(Kbase + (size_t)(j0 + sr) * DB) + colb);
        vreg = *(const s16x8*)((const char*)(Vbase + (size_t)sr * SB + j0) + colb);
    };
    auto STORE = [&](int buf) {
        *(s16x8*)((char*)&Klds[buf][0] + sr * 128 + (colb ^ swz)) = kreg;
        *(s16x8*)((char*)&Vlds[buf][0] + sr * 128 + (colb ^ swz)) = vreg;
    };
    auto COMPUTE = [&](int buf, unsigned long long mw64) {
        // QK^T swapped: sc[jf] lane(c,g) reg r = score[k=j0+jf*16+g*4+r][q=qrow]
        f32x4 sc[4];
        __builtin_amdgcn_s_setprio(1);
#pragma unroll
        for (int jf = 0; jf < 4; ++jf) {
            sc[jf] = (f32x4){0.f, 0.f, 0.f, 0.f};
#pragma unroll
            for (int ks = 0; ks < 2; ++ks) {
                s16x8 kf = *(const s16x8*)((char*)&Klds[buf][0] + (jf * 16 + c) * 128 +
                                           ((ks * 64 + g * 16) ^ ((c & 7) << 4)));
                sc[jf] = mfma16(kf, qf[ks], sc[jf]);
            }
        }
        __builtin_amdgcn_s_setprio(0);

        const unsigned long long mw = mw64 >> (g * 4);
        const unsigned int nib[4] = {
            (unsigned int)mw & 0xFu, (unsigned int)(mw >> 16) & 0xFu,
            (unsigned int)(mw >> 32) & 0xFu, (unsigned int)(mw >> 48) & 0xFu };

        s16x4 pf4[4];
#pragma unroll
        for (int jf = 0; jf < 4; ++jf) {
            float e[4];
#pragma unroll
            for (int r = 0; r < 4; ++r)
                e[r] = ((nib[jf] >> r) & 1u) ? 0.f : __builtin_amdgcn_exp2f(sc[jf][r]);
            rowacc += (e[0] + e[1]) + (e[2] + e[3]);
            union { unsigned int u[2]; s16x4 v; } pk;
            pk.u[0] = cvtpk(e[0], e[1]);
            pk.u[1] = cvtpk(e[2], e[3]);
            pf4[jf] = pk.v;
        }

        // PV: out[q][d] += P[q][k] V^T[d][k], 16x16x16; pf4 is already A-layout.
        __builtin_amdgcn_s_setprio(1);
#pragma unroll
        for (int df = 0; df < 4; ++df) {
#pragma unroll
            for (int jf = 0; jf < 4; ++jf) {
                s16x4 vf = *(const s16x4*)((char*)&Vlds[buf][0] + (df * 16 + c) * 128 +
                                           ((jf * 32 + g * 8) ^ ((c & 7) << 4)));
                acc[df] = mfma16x16(pf4[jf], vf, acc[df]);
            }
        }
        __builtin_amdgcn_s_setprio(0);
    };

    // ---- pipelined main loop: LOAD -> COMPUTE -> STORE -> barrier ----
    unsigned long long mwcur = mbits[mrowbase];
    LOAD(0);
    STORE(0);
    __syncthreads();
    int cur = 0;
    for (int jt = 0; jt < SB / 64 - 1; ++jt) {
        LOAD((jt + 1) * 64);                     // in flight across COMPUTE
        unsigned long long mwnext = mbits[mrowbase + jt + 1];
        COMPUTE(cur, mwcur);
        STORE(cur ^ 1);                          // consumes loads (vmcnt wait)
        __syncthreads();                         // nothing left pending
        mwcur = mwnext;
        cur ^= 1;
    }
    COMPUTE(cur, mwcur);

    // total rowsum for q=c: butterfly over lane bits 4,5 (the g dimension)
    rowacc += __shfl_xor(rowacc, 16);
    rowacc += __shfl_xor(rowacc, 32);
    const float inv = 1.0f / rowacc;
    if (lane < 16) invbuf[(size_t)bh * SB + i0 + w * 16 + c] = inv;   // g==0

    float ir[4];
#pragma unroll
    for (int r = 0; r < 4; ++r) ir[r] = __shfl(inv, g * 4 + r);

#pragma unroll
    for (int df = 0; df < 4; ++df) {
#pragma unroll
        for (int r = 0; r < 4; ++r) {
            const int s_ = i0 + w * 16 + g * 4 + r;
            concat[(size_t)(b * SB + s_) * CB + h * DB + df * 16 + c] =
                (unsigned short)f2bf(acc[df][r] * ir[r]);
        }
    }
}

// ---------------------------------------------------------------------------
// Merged phase-2 kernel, 1-D grid with XCD-aware bh chunking (R15 proven):
// bid < 8192: attn-write. xcd = bid&7 owns bh {2*xcd, 2*xcd+1} -> per-XCD K
//   working set 2 MB (L2-resident). Within bh: 64 q-blocks x 8 k-chunks.
//   Recompute scores, normalize with invbuf, per-wave LDS transpose,
//   coalesced nontemporal 256B stores.
// bid >= 8192: final projection GEMM (dispatches last -> tail fill).
// ---------------------------------------------------------------------------
__global__ __launch_bounds__(256) void attn_final_kernel(
    const unsigned short* __restrict__ Qh, const unsigned short* __restrict__ Kh,
    const unsigned long long* __restrict__ mbits, const float* __restrict__ invbuf,
    float* __restrict__ attnO,
    const unsigned short* __restrict__ Ain, const float* __restrict__ W,
    const float* __restrict__ bias, float* __restrict__ out)
{
    const int bid = blockIdx.x;
    if (bid >= 8192) {
        // ---- final projection: fid -> (m0, n0) over 64 x 8 tiles ----
        const int fid = bid - 8192;
        __shared__ __align__(16) short As[128 * 40];
        __shared__ __align__(16) short Bs[64 * 40];
        const int t = threadIdx.x;
        const int w = t >> 6, lane = t & 63, g = lane >> 4, c = lane & 15;
        const int wr = w >> 1, wc = w & 1;
        const int m0 = (fid >> 3) * 128, n0 = (fid & 7) * 64;

        f32x4 acc[4][2];
#pragma unroll
        for (int i = 0; i < 4; ++i)
#pragma unroll
            for (int j = 0; j < 2; ++j) acc[i][j] = (f32x4){0.f, 0.f, 0.f, 0.f};

        for (int k0 = 0; k0 < CB; k0 += 32) {
            __syncthreads();
#pragma unroll
            for (int i = 0; i < 2; ++i) {
                int idx = t + i * 256; int r = idx >> 2, ch = idx & 3;
                *(s16x8*)&As[r * 40 + ch * 8] =
                    *(const s16x8*)(Ain + (size_t)(m0 + r) * CB + k0 + ch * 8);
            }
#pragma unroll
            for (int i = 0; i < 2; ++i) {
                int idx = t + i * 256; int r = idx >> 3, c4 = idx & 7;
                float4 v = *(const float4*)(W + (size_t)(n0 + r) * CB + k0 + c4 * 4);
                s16x4 p; p[0] = f2bf(v.x); p[1] = f2bf(v.y); p[2] = f2bf(v.z); p[3] = f2bf(v.w);
                *(s16x4*)&Bs[r * 40 + c4 * 4] = p;
            }
            __syncthreads();
            const int koff = g * 8;
            s16x8 a[4], bb[2];
#pragma unroll
            for (int mf = 0; mf < 4; ++mf)
                a[mf] = *(const s16x8*)&As[(wr * 64 + mf * 16 + c) * 40 + koff];
#pragma unroll
            for (int nf = 0; nf < 2; ++nf)
                bb[nf] = *(const s16x8*)&Bs[(wc * 32 + nf * 16 + c) * 40 + koff];
#pragma unroll
            for (int mf = 0; mf < 4; ++mf)
#pragma unroll
                for (int nf = 0; nf < 2; ++nf)
                    acc[mf][nf] = mfma16(a[mf], bb[nf], acc[mf][nf]);
        }

#pragma unroll
        for (int nf = 0; nf < 2; ++nf) {
            const int n = n0 + wc * 32 + nf * 16 + c;
            const float bv = bias[n];
#pragma unroll
            for (int mf = 0; mf < 4; ++mf) {
#pragma unroll
                for (int r = 0; r < 4; ++r) {
                    int m = m0 + wr * 64 + mf * 16 + g * 4 + r;
                    out[(size_t)m * CB + n] = acc[mf][nf][r] + bv;
                }
            }
        }
        return;
    }

    // ---- attn-write, XCD-chunked ----
    __shared__ __align__(16) float TP[4][16 * 64];   // 4 KB per wave

    const int t = threadIdx.x, w = t >> 6, lane = t & 63, g = lane >> 4, c = lane & 15;
    const int xcd = bid & 7, rest = bid >> 3;        // rest in [0,1024)
    const size_t bh = (size_t)(xcd * 2 + (rest >> 9));  // 2 bh per xcd
    const int sub = rest & 511;                      // 64 q-blocks x 8 k-chunks
    const int q0 = (sub >> 3) * 64;
    const int ks0 = (sub & 7) * 512 + w * 128;

    const unsigned short* Qb_ = Qh + (bh * SB + q0) * DB;
    const unsigned short* Kb_ = Kh + bh * SB * DB;
    float* aO = attnO + bh * (size_t)SB * SB;
    char* tp = (char*)&TP[w][0];

    s16x8 qf[4][2];
    float invv[4];
    size_t mrb[4];
#pragma unroll
    for (int qi = 0; qi < 4; ++qi) {
#pragma unroll
        for (int ks = 0; ks < 2; ++ks)
            qf[qi][ks] = *(const s16x8*)(Qb_ + (size_t)(qi * 16 + c) * DB + ks * 32 + g * 8);
        invv[qi] = invbuf[bh * SB + q0 + qi * 16 + c];
        mrb[qi] = (size_t)(q0 + qi * 16 + c) * (SB / 64);
    }

#pragma unroll
    for (int kc = 0; kc < 2; ++kc) {
        const int kch = ks0 + kc * 64;
        s16x8 kf[4][2];
#pragma unroll
        for (int jf = 0; jf < 4; ++jf)
#pragma unroll
            for (int ks = 0; ks < 2; ++ks)
                kf[jf][ks] = *(const s16x8*)(Kb_ + (size_t)(kch + jf * 16 + c) * DB + ks * 32 + g * 8);

#pragma unroll
        for (int qi = 0; qi < 4; ++qi) {
            f32x4 sc[4];
#pragma unroll
            for (int jf = 0; jf < 4; ++jf) {
                sc[jf] = (f32x4){0.f, 0.f, 0.f, 0.f};
#pragma unroll
                for (int ks = 0; ks < 2; ++ks)
                    sc[jf] = mfma16(kf[jf][ks], qf[qi][ks], sc[jf]);
            }
            unsigned long long mw = mbits[mrb[qi] + (kch >> 6)] >> (g * 4);
            const unsigned int nib[4] = {
                (unsigned int)mw & 0xFu, (unsigned int)(mw >> 16) & 0xFu,
                (unsigned int)(mw >> 32) & 0xFu, (unsigned int)(mw >> 48) & 0xFu };
            const float iv = invv[qi];

            // stage normalized tile into per-wave LDS: TP[q=c][k], swizzled
#pragma unroll
            for (int jf = 0; jf < 4; ++jf) {
                f32x4 o;
#pragma unroll
                for (int r = 0; r < 4; ++r)
                    o[r] = ((nib[jf] >> r) & 1u) ? 0.f : __builtin_amdgcn_exp2f(sc[jf][r]) * iv;
                *(f32x4*)(tp + c * 256 + ((jf * 64 + g * 16) ^ (c << 4))) = o;
            }

            // coalesced writeback: inst i covers rows i*4+g, 256B contiguous/row
            const size_t gbase = (size_t)(q0 + qi * 16) * SB + kch;
#pragma unroll
            for (int i = 0; i < 4; ++i) {
                const int rr = i * 4 + g;
                f32x4 vv = *(const f32x4*)(tp + rr * 256 + ((c * 16) ^ (rr << 4)));
                __builtin_nontemporal_store(vv, (f32x4*)(aO + gbase + (size_t)rr * SB + c * 4));
            }
        }
    }
}

extern "C" void kernel_launch(void* const* d_in, const int* in_sizes, int n_in,
                              void* d_out, int out_size, void* d_ws, size_t ws_size,
                              hipStream_t stream) {
    const float* q    = (const float*)d_in[0];
    const float* k    = (const float*)d_in[1];
    const float* v    = (const float*)d_in[2];
    const float* mask = (const float*)d_in[3];
    const float* wq   = (const float*)d_in[4];
    const float* bq   = (const float*)d_in[5];
    const float* wk   = (const float*)d_in[6];
    const float* bk   = (const float*)d_in[7];
    const float* wv   = (const float*)d_in[8];
    const float* bv   = (const float*)d_in[9];
    const float* wo   = (const float*)d_in[10];
    const float* bo   = (const float*)d_in[11];

    const size_t NE = (size_t)BB * HB * SB * DB;  // 4,194,304 elements
    unsigned short* Qh     = (unsigned short*)d_ws;
    unsigned short* Kh     = Qh + NE;
    unsigned short* Vt     = Kh + NE;
    unsigned short* concat = Vt + NE;
    unsigned long long* mbits = (unsigned long long*)((char*)d_ws + 4 * NE * sizeof(unsigned short));
    float* invbuf = (float*)((char*)d_ws + 4 * NE * sizeof(unsigned short) + (size_t)SB * SB / 8);

    float* outp  = (float*)d_out;
    float* attnp = outp + (size_t)BB * SB * CB;

    // z: 0..2 = Q/K/V projection (128x128 tiles), 3..258 = mask bitmask slices
    qkv_mask_kernel<<<dim3(64, 4, 259), 256, 0, stream>>>(
        q, k, v, wq, wk, wv, bq, bk, bv, Qh, Kh, Vt, mask, mbits);
    flash_kernel<<<dim3(512, 1, 1), 512, 0, stream>>>(Qh, Kh, Vt, mbits, concat, invbuf);
    // 1-D: bid 0..8191 = attn-write (XCD-chunked), 8192..8703 = final proj
    attn_final_kernel<<<dim3(8704, 1, 1), 256, 0, stream>>>(
        Qh, Kh, mbits, invbuf, attnp, concat, wo, bo, outp);
}

// Round 17
// 389.984 us; speedup vs baseline: 1.0640x; 1.0177x over previous
//
#include <hip/hip_runtime.h>
#include <hip/hip_bf16.h>
#include <cstdint>

// Problem constants: B=2, S=4096, C=512, H=8, D=64
#define SB 4096
#define CB 512
#define HB 8
#define DB 64
#define BB 2

// 0.125 * log2(e): folded into Q projection so softmax uses exp2 directly.
#define QSCALE 0.18033688011112042f

typedef __attribute__((ext_vector_type(8))) short s16x8;
typedef __attribute__((ext_vector_type(4))) short s16x4;
typedef __attribute__((ext_vector_type(4))) float f32x4;

__device__ __forceinline__ short f2bf(float f) {
    union { float f; unsigned int u; } v; v.f = f;
    unsigned int r = v.u + 0x7fffu + ((v.u >> 16) & 1u);
    return (short)(r >> 16);
}

// pack two f32 -> bf16 pair (S0 in low half), RNE
__device__ __forceinline__ unsigned int cvtpk(float lo, float hi) {
    unsigned int r;
    asm("v_cvt_pk_bf16_f32 %0, %1, %2" : "=v"(r) : "v"(lo), "v"(hi));
    return r;
}

__device__ __forceinline__ f32x4 mfma16(s16x8 a, s16x8 b, f32x4 c) {
    return __builtin_amdgcn_mfma_f32_16x16x32_bf16(a, b, c, 0, 0, 0);
}

// K=16 bf16 MFMA via inline asm (A/B: 4 bf16 per lane, chunk (lane>>4)*4)
__device__ __forceinline__ f32x4 mfma16x16(s16x4 a, s16x4 b, f32x4 c) {
    asm("v_mfma_f32_16x16x16_bf16 %0, %1, %2, %0" : "+v"(c) : "v"(a), "v"(b));
    return c;
}

// ---------------------------------------------------------------------------
// QKV projection + mask-bitmask (one launch). 128x128 proj tile (R16-proven).
// z==0: Q -> bf16 [b,h,s,d] scaled by QSCALE
// z==1: K -> bf16 [b,h,s,d]
// z==2: V -> bf16 [b,h,d,s]  (transposed)
// z>=3: mask -> bitmask chunks (overlaps the proj GEMM; independent work)
// ---------------------------------------------------------------------------
__global__ __launch_bounds__(256) void qkv_mask_kernel(
    const float* __restrict__ q, const float* __restrict__ k, const float* __restrict__ v,
    const float* __restrict__ wq, const float* __restrict__ wk, const float* __restrict__ wv,
    const float* __restrict__ bq, const float* __restrict__ bk, const float* __restrict__ bv,
    unsigned short* __restrict__ Qh, unsigned short* __restrict__ Kh,
    unsigned short* __restrict__ Vt,
    const float* __restrict__ mask, unsigned long long* __restrict__ bits)
{
    const int z = blockIdx.z;
    if (z >= 3) {
        // mask -> bitmask: 256 slices x (64x4 blocks) x 256 threads = 16.7M elems
        size_t idx = (((size_t)(z - 3) * 256) + blockIdx.y * 64 + blockIdx.x) * 256
                     + threadIdx.x;
        float mv = mask[idx];
        unsigned long long bmask = __ballot(mv != 0.0f);
        if ((threadIdx.x & 63) == 0) bits[idx >> 6] = bmask;
        return;
    }

    const float* X = (z == 0) ? q : (z == 1) ? k : v;
    const float* W = (z == 0) ? wq : (z == 1) ? wk : wv;
    const float* bias = (z == 0) ? bq : (z == 1) ? bk : bv;
    unsigned short* dst = (z == 0) ? Qh : (z == 1) ? Kh : Vt;
    const float oscale = (z == 0) ? QSCALE : 1.0f;
    const int which = (z == 2) ? 2 : 0;

    __shared__ __align__(16) short As[128 * 40];
    __shared__ __align__(16) short Bs[128 * 40];
    const int t = threadIdx.x;
    const int w = t >> 6, lane = t & 63, g = lane >> 4, c = lane & 15;
    const int wr = w >> 1, wc = w & 1;
    const int m0 = blockIdx.x * 128, n0 = blockIdx.y * 128;

    f32x4 acc[4][4];
#pragma unroll
    for (int i = 0; i < 4; ++i)
#pragma unroll
        for (int j = 0; j < 4; ++j) acc[i][j] = (f32x4){0.f, 0.f, 0.f, 0.f};

    for (int k0 = 0; k0 < CB; k0 += 32) {
        __syncthreads();
#pragma unroll
        for (int i = 0; i < 4; ++i) {
            int idx = t + i * 256; int r = idx >> 3, c4 = idx & 7;
            float4 vv = *(const float4*)(X + (size_t)(m0 + r) * CB + k0 + c4 * 4);
            s16x4 p; p[0] = f2bf(vv.x); p[1] = f2bf(vv.y); p[2] = f2bf(vv.z); p[3] = f2bf(vv.w);
            *(s16x4*)&As[r * 40 + c4 * 4] = p;
        }
#pragma unroll
        for (int i = 0; i < 4; ++i) {
            int idx = t + i * 256; int r = idx >> 3, c4 = idx & 7;
            float4 vv = *(const float4*)(W + (size_t)(n0 + r) * CB + k0 + c4 * 4);
            s16x4 p; p[0] = f2bf(vv.x); p[1] = f2bf(vv.y); p[2] = f2bf(vv.z); p[3] = f2bf(vv.w);
            *(s16x4*)&Bs[r * 40 + c4 * 4] = p;
        }
        __syncthreads();
        const int koff = g * 8;
        s16x8 a[4], bb[4];
#pragma unroll
        for (int mf = 0; mf < 4; ++mf)
            a[mf] = *(const s16x8*)&As[(wr * 64 + mf * 16 + c) * 40 + koff];
#pragma unroll
        for (int nf = 0; nf < 4; ++nf)
            bb[nf] = *(const s16x8*)&Bs[(wc * 64 + nf * 16 + c) * 40 + koff];
#pragma unroll
        for (int mf = 0; mf < 4; ++mf)
#pragma unroll
            for (int nf = 0; nf < 4; ++nf)
                acc[mf][nf] = mfma16(a[mf], bb[nf], acc[mf][nf]);
    }

#pragma unroll
    for (int nf = 0; nf < 4; ++nf) {
        const int n = n0 + wc * 64 + nf * 16 + c;
        const float bv2 = bias[n];
        const int h = n >> 6, d = n & 63;
#pragma unroll
        for (int mf = 0; mf < 4; ++mf) {
#pragma unroll
            for (int r = 0; r < 4; ++r) {
                int m = m0 + wr * 64 + mf * 16 + g * 4 + r;
                float val = (acc[mf][nf][r] + bv2) * oscale;
                int b = m >> 12, s = m & (SB - 1);
                size_t off;
                if (which == 0) off = (((size_t)(b * HB + h)) * SB + s) * DB + d;
                else            off = (((size_t)(b * HB + h)) * DB + d) * SB + s;
                dst[off] = (unsigned short)f2bf(val);
            }
        }
    }
}

// ---------------------------------------------------------------------------
// Flash kernel (phase 1) — R13 config, setprio removed (m190: setprio is
// null-to-negative on barrier-locked multi-wave loops). 8 waves / 128 q-rows
// per block, 512 blocks, XCD-aware map (bh {2*xcd,2*xcd+1} per XCD).
//   loop: LOAD(t+1) -> COMPUTE(t,cur) -> STORE(cur^1) -> barrier
// Swapped-operand QK (out[k][q]); per-lane rowsum; PV via 16x16x16 MFMA on
// packed score regs. K/V LDS tiles XOR-swizzled (byte ^= (row&7)<<4).
// Q is pre-scaled by 0.125*log2(e), so e = exp2(QK) directly.
// ---------------------------------------------------------------------------
__global__ __launch_bounds__(512) void flash_kernel(
    const unsigned short* __restrict__ Qh, const unsigned short* __restrict__ Kh,
    const unsigned short* __restrict__ Vt, const unsigned long long* __restrict__ mbits,
    unsigned short* __restrict__ concat, float* __restrict__ invbuf)
{
    __shared__ __align__(16) short Klds[2][64 * 64];  // 2 x 8 KB, swizzled
    __shared__ __align__(16) short Vlds[2][64 * 64];

    const int t = threadIdx.x, w = t >> 6, lane = t & 63, g = lane >> 4, c = lane & 15;
    // XCD-aware map: 512 blocks; xcd = bid&7 owns bh {2*xcd, 2*xcd+1}.
    const int bid = blockIdx.x;
    const int xcd = bid & 7, idx = bid >> 3;          // idx in [0,64)
    const int bh = xcd * 2 + (idx >> 5);              // 2 bh per xcd
    const int qb = idx & 31;                          // 32 q-blocks per bh
    const int b = bh >> 3, h = bh & 7;
    const int i0 = qb * 128;

    const unsigned short* Qbase = Qh + ((size_t)bh * SB + i0 + w * 16) * DB;
    const unsigned short* Kbase = Kh + (size_t)bh * SB * DB;
    const unsigned short* Vbase = Vt + (size_t)bh * DB * SB;

    // Q fragments (B-operand): lane c holds Q row (i0+w*16+c), chunk ks*32+g*8
    s16x8 qf[2];
#pragma unroll
    for (int ks = 0; ks < 2; ++ks)
        qf[ks] = *(const s16x8*)(Qbase + (size_t)c * DB + ks * 32 + g * 8);

    const int qrow = i0 + w * 16 + c;
    const size_t mrowbase = (size_t)qrow * (SB / 64);
    float rowacc = 0.f;
    f32x4 acc[4];
#pragma unroll
    for (int df = 0; df < 4; ++df) acc[df] = (f32x4){0.f, 0.f, 0.f, 0.f};

    // staging: 512 threads, one 16B K-chunk + one 16B V-chunk each per tile
    const int sr = t >> 3;                 // row 0..63
    const int colb = (t & 7) * 16;         // byte offset within 128B row
    const int swz = (sr & 7) << 4;

    s16x8 kreg, vreg;                      // staging registers

    auto LOAD = [&](int j0) {
        kreg = *(const s16x8*)((const char*)(Kbase + (size_t)(j0 + sr) * DB) + colb);
        vreg = *(const s16x8*)((const char*)(Vbase + (size_t)sr * SB + j0) + colb);
    };
    auto STORE = [&](int buf) {
        *(s16x8*)((char*)&Klds[buf][0] + sr * 128 + (colb ^ swz)) = kreg;
        *(s16x8*)((char*)&Vlds[buf][0] + sr * 128 + (colb ^ swz)) = vreg;
    };
    auto COMPUTE = [&](int buf, unsigned long long mw64) {
        // QK^T swapped: sc[jf] lane(c,g) reg r = score[k=j0+jf*16+g*4+r][q=qrow]
        f32x4 sc[4];
#pragma unroll
        for (int jf = 0; jf < 4; ++jf) {
            sc[jf] = (f32x4){0.f, 0.f, 0.f, 0.f};
#pragma unroll
            for (int ks = 0; ks < 2; ++ks) {
                s16x8 kf = *(const s16x8*)((char*)&Klds[buf][0] + (jf * 16 + c) * 128 +
                                           ((ks * 64 + g * 16) ^ ((c & 7) << 4)));
                sc[jf] = mfma16(kf, qf[ks], sc[jf]);
            }
        }

        const unsigned long long mw = mw64 >> (g * 4);
        const unsigned int nib[4] = {
            (unsigned int)mw & 0xFu, (unsigned int)(mw >> 16) & 0xFu,
            (unsigned int)(mw >> 32) & 0xFu, (unsigned int)(mw >> 48) & 0xFu };

        s16x4 pf4[4];
#pragma unroll
        for (int jf = 0; jf < 4; ++jf) {
            float e[4];
#pragma unroll
            for (int r = 0; r < 4; ++r)
                e[r] = ((nib[jf] >> r) & 1u) ? 0.f : __builtin_amdgcn_exp2f(sc[jf][r]);
            rowacc += (e[0] + e[1]) + (e[2] + e[3]);
            union { unsigned int u[2]; s16x4 v; } pk;
            pk.u[0] = cvtpk(e[0], e[1]);
            pk.u[1] = cvtpk(e[2], e[3]);
            pf4[jf] = pk.v;
        }

        // PV: out[q][d] += P[q][k] V^T[d][k], 16x16x16; pf4 is already A-layout.
#pragma unroll
        for (int df = 0; df < 4; ++df) {
#pragma unroll
            for (int jf = 0; jf < 4; ++jf) {
                s16x4 vf = *(const s16x4*)((char*)&Vlds[buf][0] + (df * 16 + c) * 128 +
                                           ((jf * 32 + g * 8) ^ ((c & 7) << 4)));
                acc[df] = mfma16x16(pf4[jf], vf, acc[df]);
            }
        }
    };

    // ---- pipelined main loop: LOAD -> COMPUTE -> STORE -> barrier ----
    unsigned long long mwcur = mbits[mrowbase];
    LOAD(0);
    STORE(0);
    __syncthreads();
    int cur = 0;
    for (int jt = 0; jt < SB / 64 - 1; ++jt) {
        LOAD((jt + 1) * 64);                     // in flight across COMPUTE
        unsigned long long mwnext = mbits[mrowbase + jt + 1];
        COMPUTE(cur, mwcur);
        STORE(cur ^ 1);                          // consumes loads (vmcnt wait)
        __syncthreads();                         // nothing left pending
        mwcur = mwnext;
        cur ^= 1;
    }
    COMPUTE(cur, mwcur);

    // total rowsum for q=c: butterfly over lane bits 4,5 (the g dimension)
    rowacc += __shfl_xor(rowacc, 16);
    rowacc += __shfl_xor(rowacc, 32);
    const float inv = 1.0f / rowacc;
    if (lane < 16) invbuf[(size_t)bh * SB + i0 + w * 16 + c] = inv;   // g==0

    float ir[4];
#pragma unroll
    for (int r = 0; r < 4; ++r) ir[r] = __shfl(inv, g * 4 + r);

#pragma unroll
    for (int df = 0; df < 4; ++df) {
#pragma unroll
        for (int r = 0; r < 4; ++r) {
            const int s_ = i0 + w * 16 + g * 4 + r;
            concat[(size_t)(b * SB + s_) * CB + h * DB + df * 16 + c] =
                (unsigned short)f2bf(acc[df][r] * ir[r]);
        }
    }
}

// ---------------------------------------------------------------------------
// Merged phase-2 kernel, 1-D grid with XCD-aware bh chunking (R15 proven):
// bid < 8192: attn-write. xcd = bid&7 owns bh {2*xcd, 2*xcd+1} -> per-XCD K
//   working set 2 MB (L2-resident). Within bh: 64 q-blocks x 8 k-chunks.
//   Recompute scores, normalize with invbuf, per-wave LDS transpose,
//   coalesced nontemporal 256B stores.
// bid >= 8192: final projection GEMM, 128x128 tile (R16-pattern), tail fill.
// ---------------------------------------------------------------------------
__global__ __launch_bounds__(256) void attn_final_kernel(
    const unsigned short* __restrict__ Qh, const unsigned short* __restrict__ Kh,
    const unsigned long long* __restrict__ mbits, const float* __restrict__ invbuf,
    float* __restrict__ attnO,
    const unsigned short* __restrict__ Ain, const float* __restrict__ W,
    const float* __restrict__ bias, float* __restrict__ out)
{
    const int bid = blockIdx.x;
    if (bid >= 8192) {
        // ---- final projection: 128x128 tiles over (8192 x 512) ----
        const int fid = bid - 8192;              // [0, 256)
        __shared__ __align__(16) short As[128 * 40];
        __shared__ __align__(16) short Bs[128 * 40];
        const int t = threadIdx.x;
        const int w = t >> 6, lane = t & 63, g = lane >> 4, c = lane & 15;
        const int wr = w >> 1, wc = w & 1;
        const int m0 = (fid >> 2) * 128, n0 = (fid & 3) * 128;

        f32x4 acc[4][4];
#pragma unroll
        for (int i = 0; i < 4; ++i)
#pragma unroll
            for (int j = 0; j < 4; ++j) acc[i][j] = (f32x4){0.f, 0.f, 0.f, 0.f};

        for (int k0 = 0; k0 < CB; k0 += 32) {
            __syncthreads();
#pragma unroll
            for (int i = 0; i < 2; ++i) {
                int idx = t + i * 256; int r = idx >> 2, ch = idx & 3;
                *(s16x8*)&As[r * 40 + ch * 8] =
                    *(const s16x8*)(Ain + (size_t)(m0 + r) * CB + k0 + ch * 8);
            }
#pragma unroll
            for (int i = 0; i < 4; ++i) {
                int idx = t + i * 256; int r = idx >> 3, c4 = idx & 7;
                float4 v = *(const float4*)(W + (size_t)(n0 + r) * CB + k0 + c4 * 4);
                s16x4 p; p[0] = f2bf(v.x); p[1] = f2bf(v.y); p[2] = f2bf(v.z); p[3] = f2bf(v.w);
                *(s16x4*)&Bs[r * 40 + c4 * 4] = p;
            }
            __syncthreads();
            const int koff = g * 8;
            s16x8 a[4], bb[4];
#pragma unroll
            for (int mf = 0; mf < 4; ++mf)
                a[mf] = *(const s16x8*)&As[(wr * 64 + mf * 16 + c) * 40 + koff];
#pragma unroll
            for (int nf = 0; nf < 4; ++nf)
                bb[nf] = *(const s16x8*)&Bs[(wc * 64 + nf * 16 + c) * 40 + koff];
#pragma unroll
            for (int mf = 0; mf < 4; ++mf)
#pragma unroll
                for (int nf = 0; nf < 4; ++nf)
                    acc[mf][nf] = mfma16(a[mf], bb[nf], acc[mf][nf]);
        }

#pragma unroll
        for (int nf = 0; nf < 4; ++nf) {
            const int n = n0 + wc * 64 + nf * 16 + c;
            const float bv = bias[n];
#pragma unroll
            for (int mf = 0; mf < 4; ++mf) {
#pragma unroll
                for (int r = 0; r < 4; ++r) {
                    int m = m0 + wr * 64 + mf * 16 + g * 4 + r;
                    out[(size_t)m * CB + n] = acc[mf][nf][r] + bv;
                }
            }
        }
        return;
    }

    // ---- attn-write, XCD-chunked ----
    __shared__ __align__(16) float TP[4][16 * 64];   // 4 KB per wave

    const int t = threadIdx.x, w = t >> 6, lane = t & 63, g = lane >> 4, c = lane & 15;
    const int xcd = bid & 7, rest = bid >> 3;        // rest in [0,1024)
    const size_t bh = (size_t)(xcd * 2 + (rest >> 9));  // 2 bh per xcd
    const int sub = rest & 511;                      // 64 q-blocks x 8 k-chunks
    const int q0 = (sub >> 3) * 64;
    const int ks0 = (sub & 7) * 512 + w * 128;

    const unsigned short* Qb_ = Qh + (bh * SB + q0) * DB;
    const unsigned short* Kb_ = Kh + bh * SB * DB;
    float* aO = attnO + bh * (size_t)SB * SB;
    char* tp = (char*)&TP[w][0];

    s16x8 qf[4][2];
    float invv[4];
    size_t mrb[4];
#pragma unroll
    for (int qi = 0; qi < 4; ++qi) {
#pragma unroll
        for (int ks = 0; ks < 2; ++ks)
            qf[qi][ks] = *(const s16x8*)(Qb_ + (size_t)(qi * 16 + c) * DB + ks * 32 + g * 8);
        invv[qi] = invbuf[bh * SB + q0 + qi * 16 + c];
        mrb[qi] = (size_t)(q0 + qi * 16 + c) * (SB / 64);
    }

#pragma unroll
    for (int kc = 0; kc < 2; ++kc) {
        const int kch = ks0 + kc * 64;
        s16x8 kf[4][2];
#pragma unroll
        for (int jf = 0; jf < 4; ++jf)
#pragma unroll
            for (int ks = 0; ks < 2; ++ks)
                kf[jf][ks] = *(const s16x8*)(Kb_ + (size_t)(kch + jf * 16 + c) * DB + ks * 32 + g * 8);

#pragma unroll
        for (int qi = 0; qi < 4; ++qi) {
            f32x4 sc[4];
#pragma unroll
            for (int jf = 0; jf < 4; ++jf) {
                sc[jf] = (f32x4){0.f, 0.f, 0.f, 0.f};
#pragma unroll
                for (int ks = 0; ks < 2; ++ks)
                    sc[jf] = mfma16(kf[jf][ks], qf[qi][ks], sc[jf]);
            }
            unsigned long long mw = mbits[mrb[qi] + (kch >> 6)] >> (g * 4);
            const unsigned int nib[4] = {
                (unsigned int)mw & 0xFu, (unsigned int)(mw >> 16) & 0xFu,
                (unsigned int)(mw >> 32) & 0xFu, (unsigned int)(mw >> 48) & 0xFu };
            const float iv = invv[qi];

            // stage normalized tile into per-wave LDS: TP[q=c][k], swizzled
#pragma unroll
            for (int jf = 0; jf < 4; ++jf) {
                f32x4 o;
#pragma unroll
                for (int r = 0; r < 4; ++r)
                    o[r] = ((nib[jf] >> r) & 1u) ? 0.f : __builtin_amdgcn_exp2f(sc[jf][r]) * iv;
                *(f32x4*)(tp + c * 256 + ((jf * 64 + g * 16) ^ (c << 4))) = o;
            }

            // coalesced writeback: inst i covers rows i*4+g, 256B contiguous/row
            const size_t gbase = (size_t)(q0 + qi * 16) * SB + kch;
#pragma unroll
            for (int i = 0; i < 4; ++i) {
                const int rr = i * 4 + g;
                f32x4 vv = *(const f32x4*)(tp + rr * 256 + ((c * 16) ^ (rr << 4)));
                __builtin_nontemporal_store(vv, (f32x4*)(aO + gbase + (size_t)rr * SB + c * 4));
            }
        }
    }
}

extern "C" void kernel_launch(void* const* d_in, const int* in_sizes, int n_in,
                              void* d_out, int out_size, void* d_ws, size_t ws_size,
                              hipStream_t stream) {
    const float* q    = (const float*)d_in[0];
    const float* k    = (const float*)d_in[1];
    const float* v    = (const float*)d_in[2];
    const float* mask = (const float*)d_in[3];
    const float* wq   = (const float*)d_in[4];
    const float* bq   = (const float*)d_in[5];
    const float* wk   = (const float*)d_in[6];
    const float* bk   = (const float*)d_in[7];
    const float* wv   = (const float*)d_in[8];
    const float* bv   = (const float*)d_in[9];
    const float* wo   = (const float*)d_in[10];
    const float* bo   = (const float*)d_in[11];

    const size_t NE = (size_t)BB * HB * SB * DB;  // 4,194,304 elements
    unsigned short* Qh     = (unsigned short*)d_ws;
    unsigned short* Kh     = Qh + NE;
    unsigned short* Vt     = Kh + NE;
    unsigned short* concat = Vt + NE;
    unsigned long long* mbits = (unsigned long long*)((char*)d_ws + 4 * NE * sizeof(unsigned short));
    float* invbuf = (float*)((char*)d_ws + 4 * NE * sizeof(unsigned short) + (size_t)SB * SB / 8);

    float* outp  = (float*)d_out;
    float* attnp = outp + (size_t)BB * SB * CB;

    // z: 0..2 = Q/K/V projection (128x128 tiles), 3..258 = mask bitmask slices
    qkv_mask_kernel<<<dim3(64, 4, 259), 256, 0, stream>>>(
        q, k, v, wq, wk, wv, bq, bk, bv, Qh, Kh, Vt, mask, mbits);
    flash_kernel<<<dim3(512, 1, 1), 512, 0, stream>>>(Qh, Kh, Vt, mbits, concat, invbuf);
    // 1-D: bid 0..8191 = attn-write (XCD-chunked), 8192..8447 = final proj
    attn_final_kernel<<<dim3(8448, 1, 1), 256, 0, stream>>>(
        Qh, Kh, mbits, invbuf, attnp, concat, wo, bo, outp);
}